// Round 8
// baseline (668.318 us; speedup 1.0000x reference)
//
#include <hip/hip_runtime.h>
#include <hip/hip_bf16.h>

typedef __bf16 bf16x8 __attribute__((ext_vector_type(8)));
typedef float f32x4 __attribute__((ext_vector_type(4)));
typedef unsigned short ushort4v __attribute__((ext_vector_type(4)));
typedef unsigned short ushort8v __attribute__((ext_vector_type(8)));

#define B_   16
#define C_   256
#define HW_  4096
#define E_   8
#define NBLK 1024u

__device__ inline unsigned short f2bf(float f) {
    unsigned int b = __builtin_bit_cast(unsigned int, f);
    b += 0x7FFFu + ((b >> 16) & 1u);   // RNE (inputs finite)
    return (unsigned short)(b >> 16);
}

// software grid barrier: monotonic counter, reset by hipMemsetAsync each launch.
// __threadfence() = device-scope fence (release before arrive / acquire after).
// Bounded spin: a residency failure becomes a wrong answer, not a hang.
__device__ inline void gbar(unsigned int* cnt, unsigned int target) {
    __threadfence();
    __syncthreads();
    if (threadIdx.x == 0) {
        __hip_atomic_fetch_add(cnt, 1u, __ATOMIC_RELAXED, __HIP_MEMORY_SCOPE_AGENT);
        unsigned int spins = 0;
        while (__hip_atomic_load(cnt, __ATOMIC_RELAXED,
                                 __HIP_MEMORY_SCOPE_AGENT) < target) {
            __builtin_amdgcn_s_sleep(8);
            if (++spins > 4000000u) break;   // safety valve
        }
    }
    __syncthreads();
    __threadfence();
}

// Persistent kernel. Grid (64, 16): pt = blockIdx.x (p-tile), b = blockIdx.y.
// 512 threads (8 waves), LDS 39.3 KB, VGPR<=64 -> 4 blocks/CU -> all 1024 resident.
// P1: X[b][:, p0:p0+64] -> Bs bf16 (transposed, chunk-XOR-swizzled) + pool partials.
// P2: pooled -> gates (redundant/block); Weff rows [pt*4,pt*4+4) -> ws; biasE -> LDS.
// P3: out = x + Weff[b] @ x + bias  (B from LDS, A from L2/L3-resident Weff).
__global__ __launch_bounds__(512, 8) void k_moe(const float* __restrict__ in,
                                                const float* __restrict__ Wr,
                                                const float* __restrict__ br,
                                                const float* __restrict__ Wexp,
                                                const float* __restrict__ bexp,
                                                float* __restrict__ partial,
                                                unsigned short* __restrict__ Weff,
                                                unsigned int* __restrict__ bar,
                                                float* __restrict__ out) {
    __shared__ unsigned short Bs[64 * 256];   // 32 KB [p][c] bf16, chunk-XOR-swizzled
    __shared__ unsigned int   TsU[32 * 33];   // 4.2 KB p-pair-packed staging
    __shared__ float pooledS[C_];             // 1 KB
    __shared__ float biasS[C_];               // 1 KB
    __shared__ float lgp[64];
    __shared__ float gL[E_];

    const int t  = threadIdx.x;
    const int pt = blockIdx.x;
    const int b  = blockIdx.y;
    const int n0 = pt * 64;
    const int lane = t & 63, w = t >> 6;
    const int kg = lane >> 4, lr = lane & 15;
    const float* Xb = in + ((size_t)b * C_) * HW_ + n0;

    // ---------------- phase 1: stage + pool partials ----------------
    {
        const int cl = t >> 4;              // 0..31 source c row (within pass)
        const int pq = (t & 15) * 4;        // 4 p per thread
        const int pr = t & 63;              // transpose-out p
        const int c8 = t >> 6;              // 0..7 (4-c group, wave-uniform)
#pragma unroll
        for (int pass = 0; pass < 8; ++pass) {
            float4 v = *reinterpret_cast<const float4*>(
                Xb + (size_t)(pass * 32 + cl) * HW_ + pq);
            unsigned int* tr = &TsU[cl * 33 + (t & 15) * 2];
            tr[0] = (unsigned int)f2bf(v.x) | ((unsigned int)f2bf(v.y) << 16);
            tr[1] = (unsigned int)f2bf(v.z) | ((unsigned int)f2bf(v.w) << 16);
            // per-c partial sum over this block's 64 p (16 lanes per c)
            float s = v.x + v.y + v.z + v.w;
            s += __shfl_xor(s, 1, 64);
            s += __shfl_xor(s, 2, 64);
            s += __shfl_xor(s, 4, 64);
            s += __shfl_xor(s, 8, 64);
            if ((lane & 15) == 0)
                partial[(size_t)(b * C_ + pass * 32 + cl) * 64 + pt] = s;
            __syncthreads();
            // transpose out: 4 bf16 (one 8B store) per thread
            const int half = pr & 1;
            ushort4v u;
#pragma unroll
            for (int j = 0; j < 4; ++j) {
                unsigned int wv = TsU[(c8 * 4 + j) * 33 + (pr >> 1)];
                u[j] = (unsigned short)(half ? (wv >> 16) : (wv & 0xffff));
            }
            const int lc = pass * 4 + (c8 >> 1);         // logical 8-short chunk
            const int cs = lc ^ (pr & 7);                // bijective per p-row
            *reinterpret_cast<ushort4v*>(&Bs[pr * 256 + cs * 8 + (c8 & 1) * 4]) = u;
            __syncthreads();
        }
    }

    gbar(bar, NBLK);

    // ---------------- phase 2: routing + Weff slice + biasE ----------------
    if (t < C_) {
        const float4* p4 = reinterpret_cast<const float4*>(
            partial + (size_t)(b * C_ + t) * 64);
        float s = 0.f;
#pragma unroll
        for (int j = 0; j < 16; ++j) {
            float4 v = p4[j];
            s += v.x + v.y + v.z + v.w;
        }
        pooledS[t] = s * (1.0f / HW_);
    }
    __syncthreads();
    if (t < 64) {
        const int e = t & 7, seg = t >> 3;
        float s = 0.f;
#pragma unroll
        for (int c = seg * 32; c < seg * 32 + 32; ++c)
            s += pooledS[c] * Wr[c * E_ + e];
        lgp[t] = s;
    }
    __syncthreads();
    if (t == 0) {
        float wv[E_];
        float m = -1e30f;
#pragma unroll
        for (int e = 0; e < E_; ++e) {
            float s = br[e];
#pragma unroll
            for (int k = 0; k < 8; ++k) s += lgp[k * 8 + e];
            wv[e] = s; m = fmaxf(m, s);
        }
        float sum = 0.f;
#pragma unroll
        for (int e = 0; e < E_; ++e) { wv[e] = __expf(wv[e] - m); sum += wv[e]; }
        float inv = 1.f / sum;
#pragma unroll
        for (int e = 0; e < E_; ++e) wv[e] *= inv;
        int i0 = 0;
#pragma unroll
        for (int e = 1; e < E_; ++e) if (wv[e] > wv[i0]) i0 = e;
        int i1 = -1;
#pragma unroll
        for (int e = 0; e < E_; ++e) {
            if (e == i0) continue;
            if (i1 < 0 || wv[e] > wv[i1]) i1 = e;
        }
#pragma unroll
        for (int e = 0; e < E_; ++e)
            gL[e] = (e == i0 || e == i1) ? wv[e] : 0.f;
    }
    __syncthreads();
    if (t < C_) {
        float s = 0.f;
#pragma unroll
        for (int e = 0; e < E_; ++e) s += gL[e] * bexp[e * C_ + t];
        biasS[t] = s;
    }
    {
        // Weff rows [pt*4, pt*4+4): 128 threads x 2 cols per row
        const int r = t >> 7, d = pt * 4 + r;
        const int c2 = (t & 127) * 2;
        float a0 = 0.f, a1 = 0.f;
#pragma unroll
        for (int e = 0; e < E_; ++e) {
            float ge = gL[e];
            if (ge != 0.f) {
                float2 wv = *reinterpret_cast<const float2*>(
                    Wexp + ((size_t)(e * C_ + d)) * C_ + c2);
                a0 += ge * wv.x; a1 += ge * wv.y;
            }
        }
        unsigned int o = (unsigned int)f2bf(a0) | ((unsigned int)f2bf(a1) << 16);
        *reinterpret_cast<unsigned int*>(&Weff[((size_t)(b * C_ + d)) * C_ + c2]) = o;
    }

    gbar(bar, 2u * NBLK);

    // ---------------- phase 3: GEMM ----------------
    const unsigned short* Ab = Weff + (size_t)b * C_ * C_;

    f32x4 acc[2][4];
#pragma unroll
    for (int mi = 0; mi < 2; ++mi) {
#pragma unroll
        for (int j = 0; j < 4; ++j) {
            const int row = w * 32 + mi * 16 + kg * 4 + j;
            const float bias = biasS[row];
#pragma unroll
            for (int ni = 0; ni < 4; ++ni) {
                const int p = ni * 16 + lr;
                unsigned short xv =
                    Bs[p * 256 + (((row >> 3) ^ (p & 7)) * 8) + (row & 7)];
                acc[mi][ni][j] =
                    __builtin_bit_cast(float, (unsigned int)xv << 16) + bias;
            }
        }
    }

#pragma unroll
    for (int kf = 0; kf < 8; ++kf) {
        bf16x8 af[2];
#pragma unroll
        for (int mi = 0; mi < 2; ++mi) {
            const int row = w * 32 + mi * 16 + lr;
            af[mi] = __builtin_bit_cast(bf16x8,
                *reinterpret_cast<const ushort8v*>(
                    &Ab[(size_t)row * C_ + kf * 32 + kg * 8]));
        }
#pragma unroll
        for (int ni = 0; ni < 4; ++ni) {
            const int p = ni * 16 + lr;
            const int cc = (kf * 4 + kg) ^ (p & 7);
            bf16x8 bfv = __builtin_bit_cast(bf16x8,
                *reinterpret_cast<const ushort8v*>(&Bs[p * 256 + cc * 8]));
            acc[0][ni] = __builtin_amdgcn_mfma_f32_16x16x32_bf16(
                af[0], bfv, acc[0][ni], 0, 0, 0);
            acc[1][ni] = __builtin_amdgcn_mfma_f32_16x16x32_bf16(
                af[1], bfv, acc[1][ni], 0, 0, 0);
        }
    }

    float* outB = out + ((size_t)b * C_) * HW_ + n0;
#pragma unroll
    for (int mi = 0; mi < 2; ++mi) {
#pragma unroll
        for (int j = 0; j < 4; ++j) {
            const int row = w * 32 + mi * 16 + kg * 4 + j;
            float* orow = outB + (size_t)row * HW_;
#pragma unroll
            for (int ni = 0; ni < 4; ++ni)
                orow[ni * 16 + lr] = acc[mi][ni][j];
        }
    }
}

extern "C" void kernel_launch(void* const* d_in, const int* in_sizes, int n_in,
                              void* d_out, int out_size, void* d_ws, size_t ws_size,
                              hipStream_t stream) {
    const float* in   = (const float*)d_in[0];
    const float* Wr   = (const float*)d_in[1];
    const float* br   = (const float*)d_in[2];
    const float* Wexp = (const float*)d_in[3];
    const float* bexp = (const float*)d_in[4];
    float* out = (float*)d_out;
    char* ws = (char*)d_ws;

    unsigned int* bar     = (unsigned int*)(ws);               // 64 B (memset below)
    float* partial        = (float*)(ws + 0x1000);             // 1 MB
    unsigned short* Weff  = (unsigned short*)(ws + 0x101000);  // 2 MB

    (void)hipMemsetAsync(bar, 0, 64, stream);
    hipLaunchKernelGGL(k_moe, dim3(64, B_), dim3(512), 0, stream,
                       in, Wr, br, Wexp, bexp, partial, Weff, bar, out);
}

// Round 9
// 57.198 us; speedup vs baseline: 11.6842x; 11.6842x over previous
//
#include <hip/hip_runtime.h>
#include <hip/hip_bf16.h>

typedef __bf16 bf16x8 __attribute__((ext_vector_type(8)));
typedef float f32x4 __attribute__((ext_vector_type(4)));
typedef unsigned short ushort4v __attribute__((ext_vector_type(4)));
typedef unsigned short ushort8v __attribute__((ext_vector_type(8)));

#define B_  16
#define C_  256
#define HW_ 4096
#define E_  8

__device__ inline unsigned short f2bf(float f) {
    unsigned int b = __builtin_bit_cast(unsigned int, f);
    b += 0x7FFFu + ((b >> 16) & 1u);   // RNE (inputs finite)
    return (unsigned short)(b >> 16);
}

// ---------------- K1: X -> Xt (bf16, transposed, swizzled) + pool partials -----
// Grid (64, 16), 512 threads. Block (pt,b) handles p in [pt*64, pt*64+64), all c.
// Bs layout (proven r6): row p (256 shorts), 8-short chunk cs = lc ^ (p&7).
// Bs is written verbatim to Xt so k_gemm can copy it back linearly.
__global__ __launch_bounds__(512, 8) void k_prep(const float* __restrict__ in,
                                                 float* __restrict__ partial,
                                                 unsigned short* __restrict__ Xt) {
    __shared__ unsigned short Bs[64 * 256];   // 32 KB
    __shared__ unsigned int   TsU[32 * 33];   // 4.2 KB p-pair-packed staging
    const int t  = threadIdx.x;
    const int pt = blockIdx.x;
    const int b  = blockIdx.y;
    const int p0 = pt * 64;
    const float* Xb = in + ((size_t)b * C_) * HW_ + p0;
    const int lane = t & 63;
    const int cl = t >> 4;              // 0..31 source c row (within pass)
    const int pq = (t & 15) * 4;        // 4 p per thread
    const int pr = t & 63;              // transpose-out p
    const int c8 = t >> 6;              // 0..7 (4-c group, wave-uniform)

#pragma unroll
    for (int pass = 0; pass < 8; ++pass) {
        float4 v = *reinterpret_cast<const float4*>(
            Xb + (size_t)(pass * 32 + cl) * HW_ + pq);
        unsigned int* tr = &TsU[cl * 33 + (t & 15) * 2];
        tr[0] = (unsigned int)f2bf(v.x) | ((unsigned int)f2bf(v.y) << 16);
        tr[1] = (unsigned int)f2bf(v.z) | ((unsigned int)f2bf(v.w) << 16);
        // per-c partial sum over this block's 64 p (16 lanes per c)
        float s = v.x + v.y + v.z + v.w;
        s += __shfl_xor(s, 1, 64);
        s += __shfl_xor(s, 2, 64);
        s += __shfl_xor(s, 4, 64);
        s += __shfl_xor(s, 8, 64);
        if ((lane & 15) == 0)
            partial[(size_t)(b * C_ + pass * 32 + cl) * 64 + pt] = s;
        __syncthreads();
        // transpose out: 4 bf16 (one 8B store) per thread
        const int half = pr & 1;
        ushort4v u;
#pragma unroll
        for (int j = 0; j < 4; ++j) {
            unsigned int wv = TsU[(c8 * 4 + j) * 33 + (pr >> 1)];
            u[j] = (unsigned short)(half ? (wv >> 16) : (wv & 0xffff));
        }
        const int lc = pass * 4 + (c8 >> 1);         // logical 8-short chunk
        const int cs = lc ^ (pr & 7);                // bijective per p-row
        *reinterpret_cast<ushort4v*>(&Bs[pr * 256 + cs * 8 + (c8 & 1) * 4]) = u;
        __syncthreads();
    }

    // bulk write Bs -> Xt (verbatim, fully coalesced 16B stores)
    unsigned short* dst = Xt + ((size_t)(b * HW_ + p0)) * C_;
#pragma unroll
    for (int i = 0; i < 4; ++i) {
        const int off = i * 4096 + t * 8;   // shorts
        *reinterpret_cast<ushort8v*>(dst + off) =
            *reinterpret_cast<const ushort8v*>(Bs + off);
    }
}

// ------- K2: pooled (from partials) -> gates -> Weff slice + biasE -------------
// Grid (32, 16), 256 threads. partial is L2/L3-hot (1 MB).
__global__ __launch_bounds__(256) void k_wg(const float* __restrict__ partial,
                                            const float* __restrict__ Wr,
                                            const float* __restrict__ br,
                                            const float* __restrict__ Wexp,
                                            const float* __restrict__ bexp,
                                            unsigned short* __restrict__ Weff,
                                            float* __restrict__ biasE) {
    __shared__ float pooledS[C_];      // 1 KB
    __shared__ float wrs[C_ * E_];     // 8 KB
    __shared__ float lgp[64];
    __shared__ float gL[E_];
    const int t = threadIdx.x;
    const int b = blockIdx.y, dblk = blockIdx.x;

    {
        const float4* p4 = reinterpret_cast<const float4*>(
            partial + (size_t)(b * C_ + t) * 64);
        float s = 0.f;
#pragma unroll
        for (int j = 0; j < 16; ++j) {
            float4 v = p4[j];
            s += v.x + v.y + v.z + v.w;
        }
        pooledS[t] = s * (1.0f / HW_);
    }
#pragma unroll
    for (int i = 0; i < 2; ++i)
        reinterpret_cast<float4*>(wrs)[t + i * 256] =
            reinterpret_cast<const float4*>(Wr)[t + i * 256];
    __syncthreads();
    if (t < 64) {
        const int e = t & 7, seg = t >> 3;
        float s = 0.f;
#pragma unroll
        for (int c = seg * 32; c < seg * 32 + 32; ++c)
            s += pooledS[c] * wrs[c * E_ + e];
        lgp[t] = s;
    }
    __syncthreads();
    if (t == 0) {
        float w[E_];
        float m = -1e30f;
#pragma unroll
        for (int e = 0; e < E_; ++e) {
            float s = br[e];
#pragma unroll
            for (int k = 0; k < 8; ++k) s += lgp[k * 8 + e];
            w[e] = s; m = fmaxf(m, s);
        }
        float sum = 0.f;
#pragma unroll
        for (int e = 0; e < E_; ++e) { w[e] = __expf(w[e] - m); sum += w[e]; }
        float inv = 1.f / sum;
#pragma unroll
        for (int e = 0; e < E_; ++e) w[e] *= inv;
        int i0 = 0;
#pragma unroll
        for (int e = 1; e < E_; ++e) if (w[e] > w[i0]) i0 = e;
        int i1 = -1;
#pragma unroll
        for (int e = 0; e < E_; ++e) {
            if (e == i0) continue;
            if (i1 < 0 || w[e] > w[i1]) i1 = e;
        }
#pragma unroll
        for (int e = 0; e < E_; ++e)
            gL[e] = (e == i0 || e == i1) ? w[e] : 0.f;
    }
    __syncthreads();
    if (dblk == 0) {
        float s = 0.f;
#pragma unroll
        for (int e = 0; e < E_; ++e) s += gL[e] * bexp[e * C_ + t];
        biasE[b * C_ + t] = s;
    }
    const int dloc = t >> 5, cq = t & 31;
    const int d = dblk * 8 + dloc;
#pragma unroll
    for (int half = 0; half < 2; half++) {
        const int c = (cq + half * 32) * 4;
        float4 a = {0.f, 0.f, 0.f, 0.f};
#pragma unroll
        for (int e = 0; e < E_; e++) {
            float ge = gL[e];
            if (ge != 0.f) {
                float4 wv = *reinterpret_cast<const float4*>(
                    Wexp + ((size_t)(e * C_ + d)) * C_ + c);
                a.x += ge * wv.x; a.y += ge * wv.y;
                a.z += ge * wv.z; a.w += ge * wv.w;
            }
        }
        ushort4v o = { f2bf(a.x), f2bf(a.y), f2bf(a.z), f2bf(a.w) };
        *reinterpret_cast<ushort4v*>(Weff + ((size_t)(b * C_ + d)) * C_ + c) = o;
    }
}

// ---------------- K3: out[b] = x + Weff[b] @ x + biasE[b] ----------------------
// Grid (64, 16), 512 threads (8 waves). B-tile arrives pre-transposed/swizzled in
// Xt: staging = 32 x global_load_lds dwordx4 + ONE barrier. Full K=256 resident.
__global__ __launch_bounds__(512, 8) void k_gemm(const unsigned short* __restrict__ Xt,
                                                 const unsigned short* __restrict__ Weff,
                                                 const float* __restrict__ biasE,
                                                 float* __restrict__ out) {
    __shared__ unsigned short Bs[64 * 256];   // 32 KB, swizzled (as written by k_prep)
    __shared__ float biasS[C_];               // 1 KB

    const int t  = threadIdx.x;
    const int pt = blockIdx.x;
    const int b  = blockIdx.y;
    const int n0 = pt * 64;
    const int lane = t & 63, w = t >> 6;
    const int kg = lane >> 4, lr = lane & 15;
    const unsigned short* Ab = Weff + (size_t)b * C_ * C_;
    const unsigned short* src = Xt + ((size_t)(b * HW_ + n0)) * C_;

    if (t < C_) biasS[t] = biasE[b * C_ + t];

    // stage: verbatim copy Xt tile -> Bs (wave-uniform LDS base + lane*16)
#pragma unroll
    for (int i = 0; i < 4; ++i) {
        const int chunk = i * 8 + w;               // 0..31, wave-uniform
        __builtin_amdgcn_global_load_lds(
            (const __attribute__((address_space(1))) void*)(src + chunk * 512 + lane * 8),
            (__attribute__((address_space(3))) void*)(Bs + chunk * 512), 16, 0, 0);
    }
    __syncthreads();

    // acc init: identity (from Bs) + bias
    f32x4 acc[2][4];
#pragma unroll
    for (int mi = 0; mi < 2; ++mi) {
#pragma unroll
        for (int j = 0; j < 4; ++j) {
            const int row = w * 32 + mi * 16 + kg * 4 + j;
            const float bias = biasS[row];
#pragma unroll
            for (int ni = 0; ni < 4; ++ni) {
                const int p = ni * 16 + lr;
                unsigned short xv =
                    Bs[p * 256 + (((row >> 3) ^ (p & 7)) * 8) + (row & 7)];
                acc[mi][ni][j] =
                    __builtin_bit_cast(float, (unsigned int)xv << 16) + bias;
            }
        }
    }

    // MFMA main loop: 8 k-frags; A streamed from L2-resident Weff
#pragma unroll
    for (int kf = 0; kf < 8; ++kf) {
        bf16x8 af[2];
#pragma unroll
        for (int mi = 0; mi < 2; ++mi) {
            const int row = w * 32 + mi * 16 + lr;
            af[mi] = __builtin_bit_cast(bf16x8,
                *reinterpret_cast<const ushort8v*>(
                    &Ab[(size_t)row * C_ + kf * 32 + kg * 8]));
        }
#pragma unroll
        for (int ni = 0; ni < 4; ++ni) {
            const int p = ni * 16 + lr;
            const int cc = (kf * 4 + kg) ^ (p & 7);
            bf16x8 bfv = __builtin_bit_cast(bf16x8,
                *reinterpret_cast<const ushort8v*>(&Bs[p * 256 + cc * 8]));
            acc[0][ni] = __builtin_amdgcn_mfma_f32_16x16x32_bf16(
                af[0], bfv, acc[0][ni], 0, 0, 0);
            acc[1][ni] = __builtin_amdgcn_mfma_f32_16x16x32_bf16(
                af[1], bfv, acc[1][ni], 0, 0, 0);
        }
    }

    // store
    float* outB = out + ((size_t)b * C_) * HW_ + n0;
#pragma unroll
    for (int mi = 0; mi < 2; ++mi) {
#pragma unroll
        for (int j = 0; j < 4; ++j) {
            const int row = w * 32 + mi * 16 + kg * 4 + j;
            float* orow = outB + (size_t)row * HW_;
#pragma unroll
            for (int ni = 0; ni < 4; ++ni)
                orow[ni * 16 + lr] = acc[mi][ni][j];
        }
    }
}

extern "C" void kernel_launch(void* const* d_in, const int* in_sizes, int n_in,
                              void* d_out, int out_size, void* d_ws, size_t ws_size,
                              hipStream_t stream) {
    const float* in   = (const float*)d_in[0];
    const float* Wr   = (const float*)d_in[1];
    const float* br   = (const float*)d_in[2];
    const float* Wexp = (const float*)d_in[3];
    const float* bexp = (const float*)d_in[4];
    float* out = (float*)d_out;
    char* ws = (char*)d_ws;

    float* partial        = (float*)(ws);                      // 1 MB
    unsigned short* Xt    = (unsigned short*)(ws + 0x100000);  // 32 MB
    unsigned short* Weff  = (unsigned short*)(ws + 0x2100000); // 2 MB
    float* biasE          = (float*)(ws + 0x2300000);          // 16 KB

    hipLaunchKernelGGL(k_prep, dim3(64, B_), dim3(512), 0, stream, in, partial, Xt);
    hipLaunchKernelGGL(k_wg,   dim3(32, B_), dim3(256), 0, stream,
                       partial, Wr, br, Wexp, bexp, Weff, biasE);
    hipLaunchKernelGGL(k_gemm, dim3(64, B_), dim3(512), 0, stream,
                       Xt, Weff, biasE, out);
}